// Round 8
// baseline (2892.982 us; speedup 1.0000x reference)
//
#include <hip/hip_runtime.h>
#include <cstdint>
#include <cstddef>

// Problem constants
#define BB 8
#define LL 512
#define DD 256
#define HH 8
#define DHD 64
#define NLAYER 16
#define HDH 512   // H*DH
#define IN2 2048  // 2*INNER
#define IN1 1024  // INNER
#define NBLK 256u

typedef __attribute__((ext_vector_type(8))) short short8;     // 8 x bf16 (mfma A/B frag)
typedef __attribute__((ext_vector_type(4))) float floatx4;    // mfma C/D frag
typedef __attribute__((ext_vector_type(4))) unsigned short ushort4v;
typedef unsigned short u16;

__device__ __forceinline__ floatx4 mfma16(short8 a, short8 b, floatx4 c) {
  return __builtin_amdgcn_mfma_f32_16x16x32_bf16(a, b, c, 0, 0, 0);
}

__device__ __forceinline__ u16 f2b(float f) {
  union { float f; unsigned u; } x; x.f = f;
  unsigned u = x.u + 0x7fffu + ((x.u >> 16) & 1u);  // RNE
  return (u16)(u >> 16);
}
__device__ __forceinline__ float b2f(u16 s) {
  union { unsigned u; float f; } x; x.u = ((unsigned)s) << 16;
  return x.f;
}

__device__ __forceinline__ float wave_sum(float s) {
#pragma unroll
  for (int off = 32; off; off >>= 1) s += __shfl_xor(s, off);
  return s;
}

// ---- async global->LDS (16B/lane), XOR-swizzled tiles (64-elem rows) ----------
__device__ __forceinline__ void gload_lds16(const u16* g, u16* l) {
  __builtin_amdgcn_global_load_lds((__attribute__((address_space(1))) void*)g,
                                   (__attribute__((address_space(3))) void*)l,
                                   16, 0, 0);
}

template <int NSLOTS, int NTHREADS = 256>  // NSLOTS = rows*8
__device__ __forceinline__ void stage_tile(const u16* __restrict__ g, int rowstride,
                                           u16* lds, int tid) {
  int wave = tid >> 6, lane = tid & 63;
#pragma unroll
  for (int j = 0; j < NSLOTS / NTHREADS; ++j) {
    int sbase = j * NTHREADS + wave * 64;   // wave-uniform LDS base (slots)
    int slot = sbase + lane;
    int row = slot >> 3;
    int kg = (slot & 7) ^ (row & 7);
    gload_lds16(g + (size_t)row * rowstride + kg * 8, lds + sbase * 8);
  }
}

__device__ __forceinline__ short8 ld_frag(const u16* T, int row, int kg) {
  return *(const short8*)&T[(row << 6) + (((kg ^ row) & 7) << 3)];
}

// ---- 128-elem-row variants (BK=128 tiles, 16 groups/row) ----------------------
__device__ __forceinline__ short8 ld_frag128(const u16* T, int row, int kg) {
  int pg = (kg & 8) | ((kg ^ row) & 7);
  return *(const short8*)&T[(row << 7) + (pg << 3)];
}

// ---- grid barrier (sense via monotone generation counter) ---------------------
__device__ __forceinline__ void grid_barrier(unsigned* cnt, unsigned* gen,
                                             unsigned p) {
  __syncthreads();
  if (threadIdx.x == 0) {
    __threadfence();                         // release block's writes (L2 wb)
    if (atomicAdd(cnt, 1u) == NBLK - 1) {
      atomicExch(cnt, 0u);                   // reset before release
      __threadfence();
      atomicExch(gen, p);
    } else {
      unsigned g;
      do {
        g = __hip_atomic_load(gen, __ATOMIC_RELAXED, __HIP_MEMORY_SCOPE_AGENT);
        if ((int)(g - p) >= 0) break;
        __builtin_amdgcn_s_sleep(2);
      } while (true);
    }
    __threadfence();                         // acquire (L2 inv)
  }
  __syncthreads();
}

// ---------------- LN math ----------------
__device__ __forceinline__ float4 ln_math(const float* __restrict__ x,
                                          const float* __restrict__ g,
                                          const float* __restrict__ b, int t) {
  float4 v = *(const float4*)(x + t * 4);
  float s = wave_sum(v.x + v.y + v.z + v.w);
  float mu = s * (1.0f / DD);
  float dx = v.x - mu, dy = v.y - mu, dz = v.z - mu, dw = v.w - mu;
  float ss = wave_sum(dx * dx + dy * dy + dz * dz + dw * dw);
  float r = rsqrtf(ss * (1.0f / DD) + 1e-5f);
  float4 gg = *(const float4*)(g + t * 4);
  float4 bb = *(const float4*)(b + t * 4);
  float4 o;
  o.x = dx * r * gg.x + bb.x;
  o.y = dy * r * gg.y + bb.y;
  o.z = dz * r * gg.z + bb.z;
  o.w = dw * r * gg.w + bb.w;
  return o;
}

__global__ __launch_bounds__(256) void embed_ln_kernel(
    const int* __restrict__ seq, const float* __restrict__ emb,
    const float* __restrict__ png, const float* __restrict__ pnb,
    const float* __restrict__ g1, const float* __restrict__ b1,
    float* __restrict__ X, u16* __restrict__ H) {
  int row = blockIdx.x * 4 + (threadIdx.x >> 6), t = threadIdx.x & 63;
  int tok = seq[row];
  float4 o = ln_math(emb + (size_t)tok * DD, png, pnb, t);
  *(float4*)(X + (size_t)row * DD + t * 4) = o;
  float s = wave_sum(o.x + o.y + o.z + o.w);
  float mu = s * (1.0f / DD);
  float dx = o.x - mu, dy = o.y - mu, dz = o.z - mu, dw = o.w - mu;
  float ss = wave_sum(dx * dx + dy * dy + dz * dz + dw * dw);
  float r = rsqrtf(ss * (1.0f / DD) + 1e-5f);
  float4 gg = *(const float4*)(g1 + t * 4);
  float4 bb = *(const float4*)(b1 + t * 4);
  ushort4v o4;
  o4[0] = f2b(dx * r * gg.x + bb.x);
  o4[1] = f2b(dy * r * gg.y + bb.y);
  o4[2] = f2b(dz * r * gg.z + bb.z);
  o4[3] = f2b(dw * r * gg.w + bb.w);
  *(ushort4v*)(H + (size_t)row * DD + t * 4) = o4;
}

// ---------------- weight transpose+convert for ALL layers (one dispatch) ----------
#define WBUF_LAYER 1310720
__global__ __launch_bounds__(256) void prep_weights_kernel(
    const float* __restrict__ Wq, const float* __restrict__ Wk,
    const float* __restrict__ Wv, const float* __restrict__ Wo,
    const float* __restrict__ W1, const float* __restrict__ W2,
    u16* __restrict__ wbuf_all) {
  __shared__ float tile[32][33];
  int l = blockIdx.x / 1280;
  int bx = blockIdx.x % 1280;
  int tid = threadIdx.x;
  const float* wq = Wq + (size_t)l * DD * HDH;
  const float* wk = Wk + (size_t)l * DD * HDH;
  const float* wv = Wv + (size_t)l * DD * HDH;
  const float* wo = Wo + (size_t)l * HDH * DD;
  const float* w1 = W1 + (size_t)l * DD * IN2;
  const float* w2 = W2 + (size_t)l * IN1 * DD;
  u16* wbuf = wbuf_all + (size_t)l * WBUF_LAYER;

  const float* src; int srcld; u16* dst; int dstld; int dn0, k0, scol0;
  int packW1 = 0;
  if (bx < 384) {
    int t = bx; dn0 = (t % 48) * 32; k0 = (t / 48) * 32;
    scol0 = dn0 & 511;
    src = (dn0 < 512) ? wq : ((dn0 < 1024) ? wk : wv);
    srcld = 512; dst = wbuf; dstld = 256;
  } else if (bx < 512) {
    int t = bx - 384; dn0 = (t % 8) * 32; k0 = (t / 8) * 32; scol0 = dn0;
    src = wo; srcld = 256; dst = wbuf + 393216; dstld = 512;
  } else if (bx < 1024) {
    int t = bx - 512; dn0 = (t % 64) * 32; k0 = (t / 64) * 32; scol0 = dn0;
    src = w1; srcld = 2048; dst = wbuf + 524288; dstld = 256; packW1 = 1;
  } else {
    int t = bx - 1024; dn0 = (t % 8) * 32; k0 = (t / 8) * 32; scol0 = dn0;
    src = w2; srcld = 256; dst = wbuf + 1048576; dstld = 1024;
  }
  int r = tid >> 3, c4 = (tid & 7) * 4;
  float4 v = *(const float4*)&src[(size_t)(k0 + r) * srcld + scol0 + c4];
  tile[r][c4 + 0] = v.x; tile[r][c4 + 1] = v.y;
  tile[r][c4 + 2] = v.z; tile[r][c4 + 3] = v.w;
  __syncthreads();
  int n = tid >> 3, kk = (tid & 7) * 4;
  int drow = dn0 + n;
  if (packW1) {
    if (drow < 1024) drow = ((drow >> 4) << 5) | (drow & 15);
    else { int nn = drow - 1024; drow = (((nn >> 4) << 5) + 16) | (nn & 15); }
  }
  ushort4v o4;
  o4[0] = f2b(tile[kk + 0][n]); o4[1] = f2b(tile[kk + 1][n]);
  o4[2] = f2b(tile[kk + 2][n]); o4[3] = f2b(tile[kk + 3][n]);
  *(ushort4v*)&dst[(size_t)drow * dstld + k0 + kk] = o4;
}

// ================= persistent-kernel stages (grid 256 x 512 thr) =================

// ---- QKV: 128x192 tile per block (32 m-tiles x 8 n-tiles = 256) ----
__device__ __forceinline__ void stage_qkv(
    const u16* __restrict__ hb, const u16* __restrict__ wl,
    u16* __restrict__ qk, u16* __restrict__ vT, u16* smem, int tid, int bx) {
  u16* AsA[2] = {smem, smem + 8192};
  u16* BsA[2] = {smem + 16384, smem + 28672};
  int wave = tid >> 6, lane = tid & 63;
  int lm = lane & 15, quad = lane >> 4;
  int wr = wave >> 2, wc = wave & 3;
  int m0 = (bx >> 3) * 128, n0 = (bx & 7) * 192;
  const u16* Ab = hb + (size_t)m0 * DD;
  const u16* Bb = wl + (size_t)n0 * DD;

  floatx4 acc[4][3];
#pragma unroll
  for (int mf = 0; mf < 4; ++mf)
#pragma unroll
    for (int nf = 0; nf < 3; ++nf)
#pragma unroll
      for (int r = 0; r < 4; ++r) acc[mf][nf][r] = 0.0f;

  stage_tile<1024, 512>(Ab, DD, AsA[0], tid);
  stage_tile<1536, 512>(Bb, DD, BsA[0], tid);
  __syncthreads();
#pragma unroll
  for (int it = 0; it < 4; ++it) {
    if (it < 3) {
      stage_tile<1024, 512>(Ab + (it + 1) * 64, DD, AsA[(it + 1) & 1], tid);
      stage_tile<1536, 512>(Bb + (it + 1) * 64, DD, BsA[(it + 1) & 1], tid);
    }
    const u16* Ac = AsA[it & 1];
    const u16* Bc = BsA[it & 1];
#pragma unroll
    for (int kc = 0; kc < 2; ++kc) {
      short8 af[4], bf[3];
#pragma unroll
      for (int mf = 0; mf < 4; ++mf)
        af[mf] = ld_frag(Ac, wr * 64 + mf * 16 + lm, kc * 4 + quad);
#pragma unroll
      for (int nf = 0; nf < 3; ++nf)
        bf[nf] = ld_frag(Bc, wc * 48 + nf * 16 + lm, kc * 4 + quad);
#pragma unroll
      for (int mf = 0; mf < 4; ++mf)
#pragma unroll
        for (int nf = 0; nf < 3; ++nf)
          acc[mf][nf] = mfma16(af[mf], bf[nf], acc[mf][nf]);
    }
    if (it < 3) __syncthreads();
  }
#pragma unroll
  for (int mf = 0; mf < 4; ++mf)
#pragma unroll
    for (int nf = 0; nf < 3; ++nf) {
      int colf = n0 + wc * 48 + nf * 16;  // frag-uniform (1024 % 16 == 0)
      if (colf < 1024) {
#pragma unroll
        for (int r = 0; r < 4; ++r) {
          int row = m0 + wr * 64 + mf * 16 + quad * 4 + r;
          qk[(size_t)row * 1024 + colf + lm] = f2b(acc[mf][nf][r]);
        }
      } else {
        int token0 = m0 + wr * 64 + mf * 16 + quad * 4;
        int hd = colf + lm - 1024;
        int b = token0 >> 9, key = token0 & 511;
        ushort4v p4;
#pragma unroll
        for (int r = 0; r < 4; ++r) p4[r] = f2b(acc[mf][nf][r]);
        *(ushort4v*)&vT[((size_t)(b * 8 + (hd >> 6)) * 64 + (hd & 63)) * 512 + key] = p4;
      }
    }
}

// ---- attention: block = (qb 4, h 8, b 8); wave owns 16 q rows ----
__device__ __forceinline__ void stage_attn(
    const u16* __restrict__ qk, const u16* __restrict__ vT,
    const int* __restrict__ mask_raw, u16* __restrict__ O,
    u16* smem, int tid, int bx) {
  u16* Ks2[2] = {smem, smem + 4096};
  u16* Vs2[2] = {smem + 8192, smem + 12288};
  u16* Ps = smem + 16384;                 // [8][16][72]
  float* madd = (float*)(smem + 25600);   // 64 floats

  const int wave = tid >> 6, lane = tid & 63;
  const int lm = lane & 15, quad = lane >> 4;
  const int qb = bx & 3, h = (bx >> 2) & 7, b = bx >> 5;
  const float slope = exp2f(-(float)(h + 1));

  int w0 = mask_raw[0];
  int mmode = (w0 == 1) ? 0 : ((w0 == 0x3f800000) ? 2 : 1);
  const int krow_base = b * LL;

  int ntv = 8;
#pragma unroll
  for (int t = 7; t >= 0; --t) {
    bool tv;
    int gi = krow_base + t * 64;
    if (mmode == 0) tv = mask_raw[gi] != 0;
    else if (mmode == 1) tv = ((const signed char*)mask_raw)[gi] != 0;
    else tv = ((const float*)mask_raw)[gi] != 0.0f;
    if (!tv) ntv = t;
  }

  const int q0 = qb * 128 + wave * 16;
  const int qg = b * LL + q0;
  const float qpos = (float)(q0 + lm);

  const u16* qp = qk + (size_t)(qg + lm) * 1024 + h * 64 + quad * 8;
  short8 qf0 = *(const short8*)qp;
  short8 qf1 = *(const short8*)(qp + 32);

  floatx4 oc[4];
#pragma unroll
  for (int nf = 0; nf < 4; ++nf)
#pragma unroll
    for (int r = 0; r < 4; ++r) oc[nf][r] = 0.0f;
  float mrow = -1e30f, lrow = 0.0f;

  const u16* kbase_p = qk + (size_t)krow_base * 1024 + 512 + h * 64;
  const u16* vbase = vT + (size_t)(b * 8 + h) * 64 * 512;

  stage_tile<512, 512>(kbase_p, 1024, Ks2[0], tid);
  stage_tile<512, 512>(vbase, 512, Vs2[0], tid);
  if (tid < 64) {
    int gi = krow_base + (ntv - 1) * 64 + tid;
    bool valid;
    if (mmode == 0) valid = mask_raw[gi] != 0;
    else if (mmode == 1) valid = ((const signed char*)mask_raw)[gi] != 0;
    else valid = ((const float*)mask_raw)[gi] != 0.0f;
    madd[tid] = valid ? 0.0f : -1e9f;
  }
  __syncthreads();

  for (int t = 0; t < ntv; ++t) {
    int k0 = t * 64;
    if (t + 1 < ntv) {
      stage_tile<512, 512>(kbase_p + (size_t)(t + 1) * 64 * 1024, 1024,
                           Ks2[(t + 1) & 1], tid);
      stage_tile<512, 512>(vbase + (t + 1) * 64, 512, Vs2[(t + 1) & 1], tid);
    }
    const u16* Kc = Ks2[t & 1];
    const u16* Vc = Vs2[t & 1];
    bool bnd = (t == ntv - 1);

    float sc[4][4];
    float tmax = -3e38f;
#pragma unroll
    for (int nt = 0; nt < 4; ++nt) {
      floatx4 pc;
#pragma unroll
      for (int r = 0; r < 4; ++r) pc[r] = 0.0f;
      short8 kf0 = ld_frag(Kc, nt * 16 + lm, quad);
      short8 kf1 = ld_frag(Kc, nt * 16 + lm, 4 + quad);
      pc = mfma16(kf0, qf0, pc);
      pc = mfma16(kf1, qf1, pc);
      float kbase = (float)(k0 + nt * 16 + quad * 4);
#pragma unroll
      for (int r = 0; r < 4; ++r) {
        float s = pc[r] * 0.125f - slope * fabsf(qpos - (kbase + r));
        sc[nt][r] = s;
      }
      if (bnd) {
        float4 ma = *(const float4*)&madd[nt * 16 + quad * 4];
#pragma unroll
        for (int r = 0; r < 4; ++r) sc[nt][r] += ((const float*)&ma)[r];
      }
#pragma unroll
      for (int r = 0; r < 4; ++r) tmax = fmaxf(tmax, sc[nt][r]);
    }
    tmax = fmaxf(tmax, __shfl_xor(tmax, 16));
    tmax = fmaxf(tmax, __shfl_xor(tmax, 32));
    float nm = fmaxf(mrow, tmax);
    float alpha = __expf(mrow - nm);
    mrow = nm;
    float rsum = 0.0f;
#pragma unroll
    for (int nt = 0; nt < 4; ++nt)
#pragma unroll
      for (int r = 0; r < 4; ++r) {
        float p = __expf(sc[nt][r] - nm);
        sc[nt][r] = p;
        rsum += p;
      }
    rsum += __shfl_xor(rsum, 16);
    rsum += __shfl_xor(rsum, 32);
    lrow = lrow * alpha + rsum;
    float av[4];
#pragma unroll
    for (int r = 0; r < 4; ++r) av[r] = __shfl(alpha, quad * 4 + r);
#pragma unroll
    for (int nf = 0; nf < 4; ++nf)
#pragma unroll
      for (int r = 0; r < 4; ++r) oc[nf][r] *= av[r];
#pragma unroll
    for (int nt = 0; nt < 4; ++nt) {
      ushort4v p4;
#pragma unroll
      for (int r = 0; r < 4; ++r) p4[r] = f2b(sc[nt][r]);
      *(ushort4v*)&Ps[(wave * 16 + lm) * 72 + nt * 16 + quad * 4] = p4;
    }
#pragma unroll
    for (int kc = 0; kc < 2; ++kc) {
      short8 af = *(const short8*)&Ps[(wave * 16 + lm) * 72 + kc * 32 + quad * 8];
#pragma unroll
      for (int nf = 0; nf < 4; ++nf) {
        short8 bv = ld_frag(Vc, nf * 16 + lm, kc * 4 + quad);
        oc[nf] = mfma16(af, bv, oc[nf]);
      }
    }
    if (t + 1 < ntv) __syncthreads();
  }
  float rl = 1.0f / lrow;
  float rv[4];
#pragma unroll
  for (int r = 0; r < 4; ++r) rv[r] = __shfl(rl, quad * 4 + r);
#pragma unroll
  for (int nf = 0; nf < 4; ++nf)
#pragma unroll
    for (int r = 0; r < 4; ++r) {
      int qq = qg + quad * 4 + r;
      O[(size_t)qq * HDH + h * 64 + nf * 16 + lm] = f2b(oc[nf][r] * rv[r]);
    }
}

// ---- full-row GEMM (16x256, BK=128) + residual + LN (+opt outproj) ----
__device__ __forceinline__ void stage_rowln(
    const u16* __restrict__ A, int lda, const u16* __restrict__ BT, int K,
    const float* __restrict__ bias, float* __restrict__ X,
    const float* __restrict__ lng, const float* __restrict__ lnb,
    u16* __restrict__ Hout,
    const float* __restrict__ Wout, const float* __restrict__ bout,
    float* __restrict__ outp, u16* smem, int tid, int bx) {
  u16* AsB[2] = {smem, smem + 2048};
  u16* BsB[2] = {smem + 4096, smem + 36864};
  int wave = tid >> 6, lane = tid & 63;
  int lm = lane & 15, quad = lane >> 4;
  int m0 = bx * 16;

  floatx4 acc[2];
#pragma unroll
  for (int nf = 0; nf < 2; ++nf)
#pragma unroll
    for (int r = 0; r < 4; ++r) acc[nf][r] = 0.0f;

  const u16* Ab = A + (size_t)m0 * lda;

  auto stageA = [&](int k0, u16* dst) {
    if (wave < 4) {  // 256 slots
      int sbase = wave * 64;
      int slot = sbase + lane;
      int row = slot >> 4, pg = slot & 15;
      int kg = (pg & 8) | ((pg ^ row) & 7);
      gload_lds16(Ab + (size_t)row * lda + k0 + kg * 8, dst + sbase * 8);
    }
  };
  auto stageB = [&](int k0, u16* dst) {
#pragma unroll
    for (int j = 0; j < 8; ++j) {  // 4096 slots / 512 thr
      int sbase = j * 512 + wave * 64;
      int slot = sbase + lane;
      int row = slot >> 4, pg = slot & 15;
      int kg = (pg & 8) | ((pg ^ row) & 7);
      gload_lds16(BT + (size_t)row * K + k0 + kg * 8, dst + sbase * 8);
    }
  };

  stageA(0, AsB[0]);
  stageB(0, BsB[0]);
  __syncthreads();
  int iters = K >> 7;
  for (int it = 0; it < iters; ++it) {
    if (it + 1 < iters) {
      stageA((it + 1) * 128, AsB[(it + 1) & 1]);
      stageB((it + 1) * 128, BsB[(it + 1) & 1]);
    }
    const u16* Ac = AsB[it & 1];
    const u16* Bc = BsB[it & 1];
#pragma unroll
    for (int kc = 0; kc < 4; ++kc) {
      short8 af = ld_frag128(Ac, lm, kc * 4 + quad);
#pragma unroll
      for (int nf = 0; nf < 2; ++nf) {
        short8 bf = ld_frag128(Bc, wave * 32 + nf * 16 + lm, kc * 4 + quad);
        acc[nf] = mfma16(af, bf, acc[nf]);
      }
    }
    if (it + 1 < iters) __syncthreads();
  }
  __syncthreads();
  float* xs = (float*)BsB[0];  // 16 KB
#pragma unroll
  for (int nf = 0; nf < 2; ++nf) {
    int col = wave * 32 + nf * 16 + lm;
    float bv = bias ? bias[col] : 0.0f;
#pragma unroll
    for (int r = 0; r < 4; ++r) {
      int row = quad * 4 + r;
      float v = acc[nf][r] + bv + X[(size_t)(m0 + row) * DD + col];
      X[(size_t)(m0 + row) * DD + col] = v;
      xs[row * DD + col] = v;
    }
  }
  __syncthreads();
  float4 gg = *(const float4*)(lng + lane * 4);
  float4 bb = *(const float4*)(lnb + lane * 4);
#pragma unroll
  for (int rr = 0; rr < 2; ++rr) {
    int row = wave * 2 + rr;
    float4 v = *(const float4*)&xs[row * DD + lane * 4];
    float s = wave_sum(v.x + v.y + v.z + v.w);
    float mu = s * (1.0f / DD);
    float dx = v.x - mu, dy = v.y - mu, dz = v.z - mu, dw = v.w - mu;
    float ss = wave_sum(dx * dx + dy * dy + dz * dz + dw * dw);
    float rc = rsqrtf(ss * (1.0f / DD) + 1e-5f);
    float o0 = dx * rc * gg.x + bb.x;
    float o1 = dy * rc * gg.y + bb.y;
    float o2 = dz * rc * gg.z + bb.z;
    float o3 = dw * rc * gg.w + bb.w;
    ushort4v o4;
    o4[0] = f2b(o0); o4[1] = f2b(o1); o4[2] = f2b(o2); o4[3] = f2b(o3);
    *(ushort4v*)(Hout + (size_t)(m0 + row) * DD + lane * 4) = o4;
    if (Wout) {
      int d0 = lane * 4;
      float s0 = o0 * Wout[d0 * 2] + o1 * Wout[(d0 + 1) * 2] +
                 o2 * Wout[(d0 + 2) * 2] + o3 * Wout[(d0 + 3) * 2];
      float s1 = o0 * Wout[d0 * 2 + 1] + o1 * Wout[(d0 + 1) * 2 + 1] +
                 o2 * Wout[(d0 + 2) * 2 + 1] + o3 * Wout[(d0 + 3) * 2 + 1];
      s0 = wave_sum(s0);
      s1 = wave_sum(s1);
      if (lane == 0) {
        outp[(size_t)(m0 + row) * 2 + 0] = s0 + bout[0];
        outp[(size_t)(m0 + row) * 2 + 1] = s1 + bout[1];
      }
    }
  }
}

// ---- FFN1 + GeGLU: 2 serial 128x128 tiles per block ----
__device__ __forceinline__ void stage_ffn1(
    const u16* __restrict__ hb, const u16* __restrict__ w1p,
    const float* __restrict__ b1l, u16* __restrict__ G,
    u16* smem, int tid, int bx) {
  u16* AsF[2] = {smem, smem + 8192};
  u16* BsF[2] = {smem + 16384, smem + 24576};
  int wave = tid >> 6, lane = tid & 63;
  int lm = lane & 15, quad = lane >> 4;
  int wr = wave >> 2, wc = wave & 3;

  for (int t2 = 0; t2 < 2; ++t2) {
    int tile = bx + t2 * 256;
    int n0 = (tile & 15) * 128, m0 = (tile >> 4) * 128;
    const u16* Ab = hb + (size_t)m0 * DD;
    const u16* Bb = w1p + (size_t)n0 * DD;
    if (t2) __syncthreads();

    floatx4 acc[4][2];
#pragma unroll
    for (int mf = 0; mf < 4; ++mf)
#pragma unroll
      for (int nf = 0; nf < 2; ++nf)
#pragma unroll
        for (int r = 0; r < 4; ++r) acc[mf][nf][r] = 0.0f;

    stage_tile<1024, 512>(Ab, DD, AsF[0], tid);
    stage_tile<1024, 512>(Bb, DD, BsF[0], tid);
    __syncthreads();
#pragma unroll
    for (int it = 0; it < 4; ++it) {
      if (it < 3) {
        stage_tile<1024, 512>(Ab + (it + 1) * 64, DD, AsF[(it + 1) & 1], tid);
        stage_tile<1024, 512>(Bb + (it + 1) * 64, DD, BsF[(it + 1) & 1], tid);
      }
      const u16* Ac = AsF[it & 1];
      const u16* Bc = BsF[it & 1];
#pragma unroll
      for (int kc = 0; kc < 2; ++kc) {
        short8 af[4], bf[2];
#pragma unroll
        for (int mf = 0; mf < 4; ++mf)
          af[mf] = ld_frag(Ac, wr * 64 + mf * 16 + lm, kc * 4 + quad);
#pragma unroll
        for (int nf = 0; nf < 2; ++nf)
          bf[nf] = ld_frag(Bc, wc * 32 + nf * 16 + lm, kc * 4 + quad);
#pragma unroll
        for (int mf = 0; mf < 4; ++mf)
#pragma unroll
          for (int nf = 0; nf < 2; ++nf)
            acc[mf][nf] = mfma16(af[mf], bf[nf], acc[mf][nf]);
      }
      if (it < 3) __syncthreads();
    }
    int p0 = (n0 + wc * 32) >> 5;  // packed pair index (32 cols = 16 val + 16 gate)
    int gcol = p0 * 16 + lm;
    float bv = b1l[gcol], bg = b1l[1024 + gcol];
#pragma unroll
    for (int mf = 0; mf < 4; ++mf)
#pragma unroll
      for (int r = 0; r < 4; ++r) {
        int row = m0 + wr * 64 + mf * 16 + quad * 4 + r;
        float val = acc[mf][0][r] + bv;
        float gate = acc[mf][1][r] + bg;
        float ge = 0.5f * gate * (1.0f + erff(gate * 0.70710678118654752440f));
        G[(size_t)row * IN1 + gcol] = f2b(val * ge);
      }
  }
}

// ---- the persistent kernel: all 16 layers, grid barriers between stages ----
__global__ __launch_bounds__(512, 2) void layers_kernel(
    const int* __restrict__ mask, const u16* __restrict__ wbuf,
    u16* __restrict__ qk, u16* __restrict__ vT,
    u16* __restrict__ obuf, u16* __restrict__ gbuf,
    u16* __restrict__ hb, float* __restrict__ x,
    const float* __restrict__ b1, const float* __restrict__ b2,
    const float* __restrict__ ln2g, const float* __restrict__ ln2b,
    const float* __restrict__ ln1g, const float* __restrict__ ln1b,
    const float* __restrict__ fng, const float* __restrict__ fnb,
    const float* __restrict__ Wout, const float* __restrict__ bout,
    float* __restrict__ out, unsigned* __restrict__ bar) {
  __shared__ __align__(16) u16 smem[69632];  // 139,264 B -> 1 block/CU
  int tid = threadIdx.x, bx = blockIdx.x;
  unsigned* cnt = bar;
  unsigned* gen = bar + 1;
  unsigned phase = 0;

#pragma unroll 1
  for (int l = 0; l < NLAYER; ++l) {
    const u16* wl = wbuf + (size_t)l * WBUF_LAYER;

    stage_qkv(hb, wl, qk, vT, smem, tid, bx);
    grid_barrier(cnt, gen, ++phase);

    stage_attn(qk, vT, mask, obuf, smem, tid, bx);
    grid_barrier(cnt, gen, ++phase);

    stage_rowln(obuf, HDH, wl + 393216, HDH, nullptr, x,
                ln2g + l * DD, ln2b + l * DD, hb,
                nullptr, nullptr, nullptr, smem, tid, bx);
    grid_barrier(cnt, gen, ++phase);

    stage_ffn1(hb, wl + 524288, b1 + (size_t)l * IN2, gbuf, smem, tid, bx);
    grid_barrier(cnt, gen, ++phase);

    const float* ng = (l < NLAYER - 1) ? (ln1g + (l + 1) * DD) : fng;
    const float* nb = (l < NLAYER - 1) ? (ln1b + (l + 1) * DD) : fnb;
    stage_rowln(gbuf, IN1, wl + 1048576, IN1, b2 + (size_t)l * DD, x, ng, nb, hb,
                (l == NLAYER - 1) ? Wout : nullptr,
                (l == NLAYER - 1) ? bout : nullptr,
                (l == NLAYER - 1) ? out : nullptr, smem, tid, bx);
    if (l < NLAYER - 1) grid_barrier(cnt, gen, ++phase);
  }
}

extern "C" void kernel_launch(void* const* d_in, const int* in_sizes, int n_in,
                              void* d_out, int out_size, void* d_ws, size_t ws_size,
                              hipStream_t stream) {
  const int* seq = (const int*)d_in[0];
  const int* mask = (const int*)d_in[1];
  const float* emb = (const float*)d_in[2];
  const float* png = (const float*)d_in[3];
  const float* pnb = (const float*)d_in[4];
  const float* ln1g = (const float*)d_in[5];
  const float* ln1b = (const float*)d_in[6];
  const float* Wq = (const float*)d_in[7];
  const float* Wk = (const float*)d_in[8];
  const float* Wv = (const float*)d_in[9];
  const float* Wo = (const float*)d_in[10];
  const float* ln2g = (const float*)d_in[11];
  const float* ln2b = (const float*)d_in[12];
  const float* W1 = (const float*)d_in[13];
  const float* b1 = (const float*)d_in[14];
  const float* W2 = (const float*)d_in[15];
  const float* b2 = (const float*)d_in[16];
  const float* fng = (const float*)d_in[17];
  const float* fnb = (const float*)d_in[18];
  const float* Wout = (const float*)d_in[19];
  const float* bout = (const float*)d_in[20];
  float* out = (float*)d_out;

  uint8_t* wsb = (uint8_t*)d_ws;
  float* x = (float*)(wsb + 0);            //  4 MB
  u16* hb = (u16*)(wsb + 4194304);         //  2 MB
  u16* wbuf = (u16*)(wsb + 6291456);       // 40 MB (all layers)
  u16* qk = (u16*)(wsb + 48234496);        //  8 MB
  u16* vT = (u16*)(wsb + 56623104);        //  4 MB
  u16* obuf = (u16*)(wsb + 60817408);      //  4 MB
  u16* gbuf = (u16*)(wsb + 65011712);      //  8 MB
  unsigned* bar = (unsigned*)(wsb + 73400320);

  const int M = BB * LL;  // 4096

  hipMemsetAsync(bar, 0, 64, stream);  // barrier counters (ws is poisoned 0xAA)
  prep_weights_kernel<<<16 * 1280, 256, 0, stream>>>(Wq, Wk, Wv, Wo, W1, W2, wbuf);
  embed_ln_kernel<<<M / 4, 256, 0, stream>>>(seq, emb, png, pnb, ln1g, ln1b, x, hb);

  layers_kernel<<<NBLK, 512, 0, stream>>>(
      mask, wbuf, qk, vT, obuf, gbuf, hb, x, b1, b2, ln2g, ln2b, ln1g, ln1b,
      fng, fnb, Wout, bout, out, bar);

  (void)in_sizes; (void)n_in; (void)out_size; (void)ws_size;
}

// Round 9
// 1251.505 us; speedup vs baseline: 2.3116x; 2.3116x over previous
//
#include <hip/hip_runtime.h>
#include <cstdint>
#include <cstddef>

// Problem constants
#define BB 8
#define LL 512
#define DD 256
#define HH 8
#define DHD 64
#define NLAYER 16
#define HDH 512   // H*DH
#define IN2 2048  // 2*INNER
#define IN1 1024  // INNER

typedef __attribute__((ext_vector_type(8))) short short8;     // 8 x bf16 (mfma A/B frag)
typedef __attribute__((ext_vector_type(4))) float floatx4;    // mfma C/D frag
typedef __attribute__((ext_vector_type(4))) unsigned short ushort4v;
typedef unsigned short u16;

__device__ __forceinline__ floatx4 mfma16(short8 a, short8 b, floatx4 c) {
  return __builtin_amdgcn_mfma_f32_16x16x32_bf16(a, b, c, 0, 0, 0);
}

__device__ __forceinline__ u16 f2b(float f) {
  union { float f; unsigned u; } x; x.f = f;
  unsigned u = x.u + 0x7fffu + ((x.u >> 16) & 1u);  // RNE
  return (u16)(u >> 16);
}
__device__ __forceinline__ float b2f(u16 s) {
  union { unsigned u; float f; } x; x.u = ((unsigned)s) << 16;
  return x.f;
}

__device__ __forceinline__ float wave_sum(float s) {
#pragma unroll
  for (int off = 32; off; off >>= 1) s += __shfl_xor(s, off);
  return s;
}

// ---- async global->LDS (16B/lane), XOR-swizzled tiles (64-elem rows) ----------
__device__ __forceinline__ void gload_lds16(const u16* g, u16* l) {
  __builtin_amdgcn_global_load_lds((__attribute__((address_space(1))) void*)g,
                                   (__attribute__((address_space(3))) void*)l,
                                   16, 0, 0);
}

template <int NSLOTS, int NTHREADS = 256>  // NSLOTS = rows*8
__device__ __forceinline__ void stage_tile(const u16* __restrict__ g, int rowstride,
                                           u16* lds, int tid) {
  int wave = tid >> 6, lane = tid & 63;
#pragma unroll
  for (int j = 0; j < NSLOTS / NTHREADS; ++j) {
    int sbase = j * NTHREADS + wave * 64;   // wave-uniform LDS base (slots)
    int slot = sbase + lane;
    int row = slot >> 3;
    int kg = (slot & 7) ^ (row & 7);
    gload_lds16(g + (size_t)row * rowstride + kg * 8, lds + sbase * 8);
  }
}

__device__ __forceinline__ short8 ld_frag(const u16* T, int row, int kg) {
  return *(const short8*)&T[(row << 6) + (((kg ^ row) & 7) << 3)];
}

// ---- 128-elem-row variants (BK=128 tiles, 16 groups/row) ----------------------
__device__ __forceinline__ short8 ld_frag128(const u16* T, int row, int kg) {
  int pg = (kg & 8) | ((kg ^ row) & 7);
  return *(const short8*)&T[(row << 7) + (pg << 3)];
}

// ---- 256-elem-row variants (full-K tiles, 32 groups/row), NTHREADS=512 --------
template <int NSLOTS>
__device__ __forceinline__ void stage_tile256(const u16* __restrict__ g,
                                              int rowstride, u16* lds, int tid) {
  int wave = tid >> 6, lane = tid & 63;
#pragma unroll
  for (int j = 0; j < NSLOTS / 512; ++j) {
    int sbase = j * 512 + wave * 64;
    int slot = sbase + lane;
    int row = slot >> 5;
    int g32 = slot & 31;
    int kg = (g32 & 24) | ((g32 ^ row) & 7);
    gload_lds16(g + (size_t)row * rowstride + kg * 8, lds + sbase * 8);
  }
}

__device__ __forceinline__ short8 ld_frag256(const u16* T, int row, int g) {
  int pg = (g & 24) | ((g ^ row) & 7);
  return *(const short8*)&T[(row << 8) + (pg << 3)];
}

// ---------------- LN math ----------------
__device__ __forceinline__ float4 ln_math(const float* __restrict__ x,
                                          const float* __restrict__ g,
                                          const float* __restrict__ b, int t) {
  float4 v = *(const float4*)(x + t * 4);
  float s = wave_sum(v.x + v.y + v.z + v.w);
  float mu = s * (1.0f / DD);
  float dx = v.x - mu, dy = v.y - mu, dz = v.z - mu, dw = v.w - mu;
  float ss = wave_sum(dx * dx + dy * dy + dz * dz + dw * dw);
  float r = rsqrtf(ss * (1.0f / DD) + 1e-5f);
  float4 gg = *(const float4*)(g + t * 4);
  float4 bb = *(const float4*)(b + t * 4);
  float4 o;
  o.x = dx * r * gg.x + bb.x;
  o.y = dy * r * gg.y + bb.y;
  o.z = dz * r * gg.z + bb.z;
  o.w = dw * r * gg.w + bb.w;
  return o;
}

__global__ __launch_bounds__(256) void embed_ln_kernel(
    const int* __restrict__ seq, const float* __restrict__ emb,
    const float* __restrict__ png, const float* __restrict__ pnb,
    const float* __restrict__ g1, const float* __restrict__ b1,
    float* __restrict__ X, u16* __restrict__ H) {
  int row = blockIdx.x * 4 + (threadIdx.x >> 6), t = threadIdx.x & 63;
  int tok = seq[row];
  float4 o = ln_math(emb + (size_t)tok * DD, png, pnb, t);
  *(float4*)(X + (size_t)row * DD + t * 4) = o;
  float s = wave_sum(o.x + o.y + o.z + o.w);
  float mu = s * (1.0f / DD);
  float dx = o.x - mu, dy = o.y - mu, dz = o.z - mu, dw = o.w - mu;
  float ss = wave_sum(dx * dx + dy * dy + dz * dz + dw * dw);
  float r = rsqrtf(ss * (1.0f / DD) + 1e-5f);
  float4 gg = *(const float4*)(g1 + t * 4);
  float4 bb = *(const float4*)(b1 + t * 4);
  ushort4v o4;
  o4[0] = f2b(dx * r * gg.x + bb.x);
  o4[1] = f2b(dy * r * gg.y + bb.y);
  o4[2] = f2b(dz * r * gg.z + bb.z);
  o4[3] = f2b(dw * r * gg.w + bb.w);
  *(ushort4v*)(H + (size_t)row * DD + t * 4) = o4;
}

// ---------------- weight transpose+convert for ALL layers (one dispatch) ----------
#define WBUF_LAYER 1310720
__global__ __launch_bounds__(256) void prep_weights_kernel(
    const float* __restrict__ Wq, const float* __restrict__ Wk,
    const float* __restrict__ Wv, const float* __restrict__ Wo,
    const float* __restrict__ W1, const float* __restrict__ W2,
    u16* __restrict__ wbuf_all) {
  __shared__ float tile[32][33];
  int l = blockIdx.x / 1280;
  int bx = blockIdx.x % 1280;
  int tid = threadIdx.x;
  const float* wq = Wq + (size_t)l * DD * HDH;
  const float* wk = Wk + (size_t)l * DD * HDH;
  const float* wv = Wv + (size_t)l * DD * HDH;
  const float* wo = Wo + (size_t)l * HDH * DD;
  const float* w1 = W1 + (size_t)l * DD * IN2;
  const float* w2 = W2 + (size_t)l * IN1 * DD;
  u16* wbuf = wbuf_all + (size_t)l * WBUF_LAYER;

  const float* src; int srcld; u16* dst; int dstld; int dn0, k0, scol0;
  int packW1 = 0;
  if (bx < 384) {
    int t = bx; dn0 = (t % 48) * 32; k0 = (t / 48) * 32;
    scol0 = dn0 & 511;
    src = (dn0 < 512) ? wq : ((dn0 < 1024) ? wk : wv);
    srcld = 512; dst = wbuf; dstld = 256;
  } else if (bx < 512) {
    int t = bx - 384; dn0 = (t % 8) * 32; k0 = (t / 8) * 32; scol0 = dn0;
    src = wo; srcld = 256; dst = wbuf + 393216; dstld = 512;
  } else if (bx < 1024) {
    int t = bx - 512; dn0 = (t % 64) * 32; k0 = (t / 64) * 32; scol0 = dn0;
    src = w1; srcld = 2048; dst = wbuf + 524288; dstld = 256; packW1 = 1;
  } else {
    int t = bx - 1024; dn0 = (t % 8) * 32; k0 = (t / 8) * 32; scol0 = dn0;
    src = w2; srcld = 256; dst = wbuf + 1048576; dstld = 1024;
  }
  int r = tid >> 3, c4 = (tid & 7) * 4;
  float4 v = *(const float4*)&src[(size_t)(k0 + r) * srcld + scol0 + c4];
  tile[r][c4 + 0] = v.x; tile[r][c4 + 1] = v.y;
  tile[r][c4 + 2] = v.z; tile[r][c4 + 3] = v.w;
  __syncthreads();
  int n = tid >> 3, kk = (tid & 7) * 4;
  int drow = dn0 + n;
  if (packW1) {
    if (drow < 1024) drow = ((drow >> 4) << 5) | (drow & 15);
    else { int nn = drow - 1024; drow = (((nn >> 4) << 5) + 16) | (nn & 15); }
  }
  ushort4v o4;
  o4[0] = f2b(tile[kk + 0][n]); o4[1] = f2b(tile[kk + 1][n]);
  o4[2] = f2b(tile[kk + 2][n]); o4[3] = f2b(tile[kk + 3][n]);
  *(ushort4v*)&dst[(size_t)drow * dstld + k0 + kk] = o4;
}

// ---------------- FUSED QKV + flash attention ----------------
// grid (4 qtiles, H, B) = 256 blocks, 512 thr. Block computes its own Q (128 rows),
// and K/V for all 512 keys of its (b,h) (4x redundant; weights LDS-resident).
// LDS (u16): Wb 32768 | Ab 16384 | Qs 9216 | Ks 4608 | Vs 4608 | Ps 9216 | madd 128
__global__ __launch_bounds__(512, 2) void qkv_attn_kernel(
    const u16* __restrict__ hb, const u16* __restrict__ wqkv,
    const int* __restrict__ mask_raw, u16* __restrict__ O) {
  __shared__ __align__(16) u16 smem[76928];   // 153,856 B -> 1 block/CU
  u16* Wb = smem;            // 128x256 (hb q-rows, then Wk|Wv)
  u16* Ab = smem + 32768;    // 64x256  (Wq, then hb key-rows per tile)
  u16* Qs = smem + 49152;    // [128][72]
  u16* Ks = smem + 58368;    // [64][72]
  u16* Vs = smem + 62976;    // [64][72]  ([d][key])
  u16* Ps = smem + 67584;    // [8][16][72]
  float* madd = (float*)(smem + 76800);

  const int tid = threadIdx.x, wave = tid >> 6, lane = tid & 63;
  const int lm = lane & 15, quad = lane >> 4;
  const int qt = blockIdx.x, h = blockIdx.y, b = blockIdx.z;
  const float slope = exp2f(-(float)(h + 1));

  int w0 = mask_raw[0];
  int mmode = (w0 == 1) ? 0 : ((w0 == 0x3f800000) ? 2 : 1);
  const int krow_base = b * LL;

  // valid tile count (mask monotone; len>=256 => ntv>=4)
  int ntv = 8;
#pragma unroll
  for (int t = 7; t >= 0; --t) {
    bool tv;
    int gi = krow_base + t * 64;
    if (mmode == 0) tv = mask_raw[gi] != 0;
    else if (mmode == 1) tv = ((const signed char*)mask_raw)[gi] != 0;
    else tv = ((const float*)mask_raw)[gi] != 0.0f;
    if (!tv) ntv = t;
  }

  // ---- Q phase: Q[128][64] = hb[qrows] @ WqT[h cols] ----
  stage_tile256<4096>(hb + (size_t)(b * LL + qt * 128) * DD, DD, Wb, tid);
  stage_tile256<2048>(wqkv + (size_t)(h * 64) * DD, DD, Ab, tid);
  __syncthreads();
  {
    floatx4 qacc[4];
#pragma unroll
    for (int nf = 0; nf < 4; ++nf)
#pragma unroll
      for (int r = 0; r < 4; ++r) qacc[nf][r] = 0.0f;
#pragma unroll
    for (int kc = 0; kc < 8; ++kc) {
      short8 af = ld_frag256(Wb, wave * 16 + lm, kc * 4 + quad);
#pragma unroll
      for (int nf = 0; nf < 4; ++nf) {
        short8 bf = ld_frag256(Ab, nf * 16 + lm, kc * 4 + quad);
        qacc[nf] = mfma16(af, bf, qacc[nf]);
      }
    }
#pragma unroll
    for (int nf = 0; nf < 4; ++nf)
#pragma unroll
      for (int r = 0; r < 4; ++r)
        Qs[(wave * 16 + quad * 4 + r) * 72 + nf * 16 + lm] = f2b(qacc[nf][r]);
  }
  // own-wave rows: no barrier needed before reading
  short8 qf0 = *(const short8*)&Qs[(wave * 16 + lm) * 72 + quad * 8];
  short8 qf1 = *(const short8*)&Qs[(wave * 16 + lm) * 72 + 32 + quad * 8];
  __syncthreads();  // hb/Wq LDS reads done -> safe to overwrite

  // stage Wk|Wv (resident) + first key-tile A + boundary mask
  stage_tile256<2048>(wqkv + (size_t)(512 + h * 64) * DD, DD, Wb, tid);
  stage_tile256<2048>(wqkv + (size_t)(1024 + h * 64) * DD, DD, Wb + 16384, tid);
  stage_tile256<2048>(hb + (size_t)(b * LL) * DD, DD, Ab, tid);
  if (tid < 64) {
    int gi = krow_base + (ntv - 1) * 64 + tid;
    bool valid;
    if (mmode == 0) valid = mask_raw[gi] != 0;
    else if (mmode == 1) valid = ((const signed char*)mask_raw)[gi] != 0;
    else valid = ((const float*)mask_raw)[gi] != 0.0f;
    madd[tid] = valid ? 0.0f : -1e9f;
  }
  __syncthreads();

  const int q0 = qt * 128 + wave * 16;
  const int qg = b * LL + q0;
  const float qpos = (float)(q0 + lm);

  floatx4 oc[4];
#pragma unroll
  for (int nf = 0; nf < 4; ++nf)
#pragma unroll
    for (int r = 0; r < 4; ++r) oc[nf][r] = 0.0f;
  float mrow = -1e30f, lrow = 0.0f;

  for (int t = 0; t < ntv; ++t) {
    int k0 = t * 64;
    // ---- K/V GEMM for this key tile (waves 0-3: K, waves 4-7: V) ----
    {
      floatx4 kv[4];
#pragma unroll
      for (int nf = 0; nf < 4; ++nf)
#pragma unroll
        for (int r = 0; r < 4; ++r) kv[nf][r] = 0.0f;
      int arow = (wave & 3) * 16 + lm;
      int bbase = (wave < 4) ? 0 : 64;
#pragma unroll
      for (int kc = 0; kc < 8; ++kc) {
        short8 af = ld_frag256(Ab, arow, kc * 4 + quad);
#pragma unroll
        for (int nf = 0; nf < 4; ++nf) {
          short8 bf = ld_frag256(Wb, bbase + nf * 16 + lm, kc * 4 + quad);
          kv[nf] = mfma16(af, bf, kv[nf]);
        }
      }
      if (wave < 4) {  // Ks[key][d]
#pragma unroll
        for (int nf = 0; nf < 4; ++nf)
#pragma unroll
          for (int r = 0; r < 4; ++r)
            Ks[((wave & 3) * 16 + quad * 4 + r) * 72 + nf * 16 + lm] =
                f2b(kv[nf][r]);
      } else {         // Vs[d][key], 4 consecutive keys per b64
#pragma unroll
        for (int nf = 0; nf < 4; ++nf) {
          ushort4v p4;
#pragma unroll
          for (int r = 0; r < 4; ++r) p4[r] = f2b(kv[nf][r]);
          *(ushort4v*)&Vs[(nf * 16 + lm) * 72 + (wave & 3) * 16 + quad * 4] = p4;
        }
      }
    }
    __syncthreads();
    // prefetch next key-tile's A rows during attention math
    if (t + 1 < ntv)
      stage_tile256<2048>(hb + (size_t)(b * LL + (t + 1) * 64) * DD, DD, Ab, tid);

    // ---- attention math (S^T = K·Q^T) ----
    bool bnd = (t == ntv - 1);
    float sc[4][4];
    float tmax = -3e38f;
#pragma unroll
    for (int nt = 0; nt < 4; ++nt) {
      floatx4 pc;
#pragma unroll
      for (int r = 0; r < 4; ++r) pc[r] = 0.0f;
      short8 kf0 = *(const short8*)&Ks[(nt * 16 + lm) * 72 + quad * 8];
      short8 kf1 = *(const short8*)&Ks[(nt * 16 + lm) * 72 + 32 + quad * 8];
      pc = mfma16(kf0, qf0, pc);
      pc = mfma16(kf1, qf1, pc);
      float kbase = (float)(k0 + nt * 16 + quad * 4);
#pragma unroll
      for (int r = 0; r < 4; ++r) {
        float s = pc[r] * 0.125f - slope * fabsf(qpos - (kbase + r));
        sc[nt][r] = s;
      }
      if (bnd) {
        float4 ma = *(const float4*)&madd[nt * 16 + quad * 4];
#pragma unroll
        for (int r = 0; r < 4; ++r) sc[nt][r] += ((const float*)&ma)[r];
      }
#pragma unroll
      for (int r = 0; r < 4; ++r) tmax = fmaxf(tmax, sc[nt][r]);
    }
    tmax = fmaxf(tmax, __shfl_xor(tmax, 16));
    tmax = fmaxf(tmax, __shfl_xor(tmax, 32));
    float nm = fmaxf(mrow, tmax);
    float alpha = __expf(mrow - nm);
    mrow = nm;
    float rsum = 0.0f;
#pragma unroll
    for (int nt = 0; nt < 4; ++nt)
#pragma unroll
      for (int r = 0; r < 4; ++r) {
        float p = __expf(sc[nt][r] - nm);
        sc[nt][r] = p;
        rsum += p;
      }
    rsum += __shfl_xor(rsum, 16);
    rsum += __shfl_xor(rsum, 32);
    lrow = lrow * alpha + rsum;
    float av[4];
#pragma unroll
    for (int r = 0; r < 4; ++r) av[r] = __shfl(alpha, quad * 4 + r);
#pragma unroll
    for (int nf = 0; nf < 4; ++nf)
#pragma unroll
      for (int r = 0; r < 4; ++r) oc[nf][r] *= av[r];
#pragma unroll
    for (int nt = 0; nt < 4; ++nt) {
      ushort4v p4;
#pragma unroll
      for (int r = 0; r < 4; ++r) p4[r] = f2b(sc[nt][r]);
      *(ushort4v*)&Ps[(wave * 16 + lm) * 72 + nt * 16 + quad * 4] = p4;
    }
#pragma unroll
    for (int kc = 0; kc < 2; ++kc) {
      short8 af = *(const short8*)&Ps[(wave * 16 + lm) * 72 + kc * 32 + quad * 8];
#pragma unroll
      for (int nf = 0; nf < 4; ++nf) {
        short8 bv = *(const short8*)&Vs[(nf * 16 + lm) * 72 + kc * 32 + quad * 8];
        oc[nf] = mfma16(af, bv, oc[nf]);
      }
    }
    __syncthreads();  // Ks/Vs reads done; also drains A(t+1) staging
  }
  float rl = 1.0f / lrow;
  float rv[4];
#pragma unroll
  for (int r = 0; r < 4; ++r) rv[r] = __shfl(rl, quad * 4 + r);
#pragma unroll
  for (int nf = 0; nf < 4; ++nf)
#pragma unroll
    for (int r = 0; r < 4; ++r) {
      int qq = qg + quad * 4 + r;
      O[(size_t)qq * HDH + h * 64 + nf * 16 + lm] = f2b(oc[nf][r] * rv[r]);
    }
}

// ---------------- W1 GEMM 128x128 + fused GeGLU (pipelined dbuf) ----------
__global__ __launch_bounds__(256) void gemm_ffn1(
    const u16* __restrict__ A, const u16* __restrict__ BTp,
    const float* __restrict__ b1, u16* __restrict__ G) {
  __shared__ __align__(16) u16 As[2][128 * 64];
  __shared__ __align__(16) u16 Bs[2][128 * 64];
  int tid = threadIdx.x;
  int wave = tid >> 6, lane = tid & 63;
  int lm = lane & 15, quad = lane >> 4;
  int wr = wave >> 1, wc = wave & 1;
  int n0 = blockIdx.x * 128, m0 = blockIdx.y * 128;
  const u16* Ab = A + (size_t)m0 * DD;
  const u16* Bb = BTp + (size_t)n0 * DD;

  floatx4 acc[4][4];
#pragma unroll
  for (int mf = 0; mf < 4; ++mf)
#pragma unroll
    for (int nf = 0; nf < 4; ++nf)
#pragma unroll
      for (int r = 0; r < 4; ++r) acc[mf][nf][r] = 0.0f;

  stage_tile<1024>(Ab, DD, As[0], tid);
  stage_tile<1024>(Bb, DD, Bs[0], tid);
  __syncthreads();
#pragma unroll
  for (int it = 0; it < 4; ++it) {
    if (it < 3) {
      stage_tile<1024>(Ab + (it + 1) * 64, DD, As[(it + 1) & 1], tid);
      stage_tile<1024>(Bb + (it + 1) * 64, DD, Bs[(it + 1) & 1], tid);
    }
    const u16* Ac = As[it & 1];
    const u16* Bc = Bs[it & 1];
#pragma unroll
    for (int kc = 0; kc < 2; ++kc) {
      short8 af[4], bf[4];
#pragma unroll
      for (int mf = 0; mf < 4; ++mf)
        af[mf] = ld_frag(Ac, wr * 64 + mf * 16 + lm, kc * 4 + quad);
#pragma unroll
      for (int nf = 0; nf < 4; ++nf)
        bf[nf] = ld_frag(Bc, wc * 64 + nf * 16 + lm, kc * 4 + quad);
#pragma unroll
      for (int mf = 0; mf < 4; ++mf)
#pragma unroll
        for (int nf = 0; nf < 4; ++nf)
          acc[mf][nf] = mfma16(af[mf], bf[nf], acc[mf][nf]);
    }
    if (it < 3) __syncthreads();
  }
  int p0 = (n0 + wc * 64) >> 5;
#pragma unroll
  for (int j = 0; j < 2; ++j) {
    int gcol = (p0 + j) * 16 + lm;
    float bv = b1[gcol], bg = b1[1024 + gcol];
#pragma unroll
    for (int mf = 0; mf < 4; ++mf)
#pragma unroll
      for (int r = 0; r < 4; ++r) {
        int row = m0 + wr * 64 + mf * 16 + quad * 4 + r;
        float val = acc[mf][2 * j][r] + bv;
        float gate = acc[mf][2 * j + 1][r] + bg;
        float ge = 0.5f * gate * (1.0f + erff(gate * 0.70710678118654752440f));
        G[(size_t)row * IN1 + gcol] = f2b(val * ge);
      }
  }
}

// ---------------- GEMM (16x256 full-row, BK=128) + residual + LN (+outproj) ----
__global__ __launch_bounds__(512) void gemm_row_ln(
    const u16* __restrict__ A, int lda, const u16* __restrict__ BT, int K,
    const float* __restrict__ bias, float* __restrict__ X,
    const float* __restrict__ lng, const float* __restrict__ lnb,
    u16* __restrict__ Hout,
    const float* __restrict__ Wout, const float* __restrict__ bout,
    float* __restrict__ outp) {
  __shared__ __align__(16) u16 As[2][16 * 128];    //  8 KB
  __shared__ __align__(16) u16 Bs[2][256 * 128];   // 128 KB
  int tid = threadIdx.x;
  int wave = tid >> 6, lane = tid & 63;
  int lm = lane & 15, quad = lane >> 4;
  int m0 = blockIdx.x * 16;

  floatx4 acc[2];
#pragma unroll
  for (int nf = 0; nf < 2; ++nf)
#pragma unroll
    for (int r = 0; r < 4; ++r) acc[nf][r] = 0.0f;

  const u16* Ab = A + (size_t)m0 * lda;

  auto stageA = [&](int k0, u16* dst) {
    if (wave < 4) {  // 256 slots
      int sbase = wave * 64;
      int slot = sbase + lane;
      int row = slot >> 4, pg = slot & 15;
      int kg = (pg & 8) | ((pg ^ row) & 7);
      gload_lds16(Ab + (size_t)row * lda + k0 + kg * 8, dst + sbase * 8);
    }
  };
  auto stageB = [&](int k0, u16* dst) {
#pragma unroll
    for (int j = 0; j < 8; ++j) {  // 4096 slots / 512 thr
      int sbase = j * 512 + wave * 64;
      int slot = sbase + lane;
      int row = slot >> 4, pg = slot & 15;
      int kg = (pg & 8) | ((pg ^ row) & 7);
      gload_lds16(BT + (size_t)row * K + k0 + kg * 8, dst + sbase * 8);
    }
  };

  stageA(0, As[0]);
  stageB(0, Bs[0]);
  __syncthreads();
  int iters = K >> 7;
  for (int it = 0; it < iters; ++it) {
    if (it + 1 < iters) {
      stageA((it + 1) * 128, As[(it + 1) & 1]);
      stageB((it + 1) * 128, Bs[(it + 1) & 1]);
    }
    const u16* Ac = As[it & 1];
    const u16* Bc = Bs[it & 1];
#pragma unroll
    for (int kc = 0; kc < 4; ++kc) {
      short8 af = ld_frag128(Ac, lm, kc * 4 + quad);
#pragma unroll
      for (int nf = 0; nf < 2; ++nf) {
        short8 bf = ld_frag128(Bc, wave * 32 + nf * 16 + lm, kc * 4 + quad);
        acc[nf] = mfma16(af, bf, acc[nf]);
      }
    }
    if (it + 1 < iters) __syncthreads();
  }
  __syncthreads();
  float* xs = (float*)Bs[0];  // 16 KB
#pragma unroll
  for (int nf = 0; nf < 2; ++nf) {
    int col = wave * 32 + nf * 16 + lm;
    float bv = bias ? bias[col] : 0.0f;
#pragma unroll
    for (int r = 0; r < 4; ++r) {
      int row = quad * 4 + r;
      float v = acc[nf][r] + bv + X[(size_t)(m0 + row) * DD + col];
      X[(size_t)(m0 + row) * DD + col] = v;
      xs[row * DD + col] = v;
    }
  }
  __syncthreads();
  float4 gg = *(const float4*)(lng + lane * 4);
  float4 bb = *(const float4*)(lnb + lane * 4);
#pragma unroll
  for (int rr = 0; rr < 2; ++rr) {
    int row = wave * 2 + rr;
    float4 v = *(const float4*)&xs[row * DD + lane * 4];
    float s = wave_sum(v.x + v.y + v.z + v.w);
    float mu = s * (1.0f / DD);
    float dx = v.x - mu, dy = v.y - mu, dz = v.z - mu, dw = v.w - mu;
    float ss = wave_sum(dx * dx + dy * dy + dz * dz + dw * dw);
    float rc = rsqrtf(ss * (1.0f / DD) + 1e-5f);
    float o0 = dx * rc * gg.x + bb.x;
    float o1 = dy * rc * gg.y + bb.y;
    float o2 = dz * rc * gg.z + bb.z;
    float o3 = dw * rc * gg.w + bb.w;
    ushort4v o4;
    o4[0] = f2b(o0); o4[1] = f2b(o1); o4[2] = f2b(o2); o4[3] = f2b(o3);
    *(ushort4v*)(Hout + (size_t)(m0 + row) * DD + lane * 4) = o4;
    if (Wout) {
      int d0 = lane * 4;
      float s0 = o0 * Wout[d0 * 2] + o1 * Wout[(d0 + 1) * 2] +
                 o2 * Wout[(d0 + 2) * 2] + o3 * Wout[(d0 + 3) * 2];
      float s1 = o0 * Wout[d0 * 2 + 1] + o1 * Wout[(d0 + 1) * 2 + 1] +
                 o2 * Wout[(d0 + 2) * 2 + 1] + o3 * Wout[(d0 + 3) * 2 + 1];
      s0 = wave_sum(s0);
      s1 = wave_sum(s1);
      if (lane == 0) {
        outp[(size_t)(m0 + row) * 2 + 0] = s0 + bout[0];
        outp[(size_t)(m0 + row) * 2 + 1] = s1 + bout[1];
      }
    }
  }
}

extern "C" void kernel_launch(void* const* d_in, const int* in_sizes, int n_in,
                              void* d_out, int out_size, void* d_ws, size_t ws_size,
                              hipStream_t stream) {
  const int* seq = (const int*)d_in[0];
  const int* mask = (const int*)d_in[1];
  const float* emb = (const float*)d_in[2];
  const float* png = (const float*)d_in[3];
  const float* pnb = (const float*)d_in[4];
  const float* ln1g = (const float*)d_in[5];
  const float* ln1b = (const float*)d_in[6];
  const float* Wq = (const float*)d_in[7];
  const float* Wk = (const float*)d_in[8];
  const float* Wv = (const float*)d_in[9];
  const float* Wo = (const float*)d_in[10];
  const float* ln2g = (const float*)d_in[11];
  const float* ln2b = (const float*)d_in[12];
  const float* W1 = (const float*)d_in[13];
  const float* b1 = (const float*)d_in[14];
  const float* W2 = (const float*)d_in[15];
  const float* b2 = (const float*)d_in[16];
  const float* fng = (const float*)d_in[17];
  const float* fnb = (const float*)d_in[18];
  const float* Wout = (const float*)d_in[19];
  const float* bout = (const float*)d_in[20];
  float* out = (float*)d_out;

  uint8_t* wsb = (uint8_t*)d_ws;
  float* x = (float*)(wsb + 0);            //  4 MB
  u16* hb = (u16*)(wsb + 4194304);         //  2 MB
  u16* wbuf = (u16*)(wsb + 6291456);       // 40 MB (all layers)
  u16* obuf = (u16*)(wsb + 48234496);      //  4 MB
  u16* gbuf = (u16*)(wsb + 52428800);      //  8 MB

  const int M = BB * LL;  // 4096

  prep_weights_kernel<<<16 * 1280, 256, 0, stream>>>(Wq, Wk, Wv, Wo, W1, W2, wbuf);
  embed_ln_kernel<<<M / 4, 256, 0, stream>>>(seq, emb, png, pnb, ln1g, ln1b, x, hb);

  for (int l = 0; l < NLAYER; ++l) {
    u16* wl = wbuf + (size_t)l * WBUF_LAYER;

    // fused: per-(b,h,qtile) Q/K/V GEMM + flash attention -> obuf
    qkv_attn_kernel<<<dim3(4, HH, BB), 512, 0, stream>>>(hb, wl, mask, obuf);

    // x += o @ Wo ; hb = ln2(x)
    gemm_row_ln<<<M / 16, 512, 0, stream>>>(
        obuf, HDH, wl + 393216, HDH, nullptr, x,
        ln2g + l * DD, ln2b + l * DD, hb, nullptr, nullptr, nullptr);

    // g = geglu(hb @ W1 + b1)
    gemm_ffn1<<<dim3(IN2 / 128, M / 128), 256, 0, stream>>>(
        hb, wl + 524288, b1 + (size_t)l * IN2, gbuf);

    // x += g @ W2 + b2 ; hb = ln1(next) or final LN (+fused outproj on last)
    const float* ng = (l < NLAYER - 1) ? (ln1g + (l + 1) * DD) : fng;
    const float* nb = (l < NLAYER - 1) ? (ln1b + (l + 1) * DD) : fnb;
    const float* wo_p = (l == NLAYER - 1) ? Wout : nullptr;
    const float* bo_p = (l == NLAYER - 1) ? bout : nullptr;
    float* out_p = (l == NLAYER - 1) ? out : nullptr;
    gemm_row_ln<<<M / 16, 512, 0, stream>>>(
        gbuf, IN1, wl + 1048576, IN1, b2 + (size_t)l * DD, x, ng, nb, hb,
        wo_p, bo_p, out_p);
  }

  (void)in_sizes; (void)n_in; (void)out_size; (void)ws_size;
}